// Round 14
// baseline (313.579 us; speedup 1.0000x reference)
//
#include <hip/hip_runtime.h>

#define NATOM 3840
#define NMOL 48
#define NPER 80
#define FD 128
#define KR 64
#define NBLOCK 5

constexpr float SR_CUT_C = 10.0f;
constexpr float KEHALF_C = 7.199822675975274f;
constexpr float LN2_C    = 0.6931471805599453f;

using bf16x8 = __attribute__((ext_vector_type(8))) short;
using f32x4  = __attribute__((ext_vector_type(4))) float;

__device__ __forceinline__ float sspf(float x) {
    return fmaxf(x, 0.0f) + __logf(1.0f + __expf(-fabsf(x))) - LN2_C;
}

__device__ __forceinline__ void split2(float v, short& hi, short& lo) {
    unsigned u = __float_as_uint(v);
    hi = (short)(u >> 16);
    float l = v - __uint_as_float(u & 0xFFFF0000u);
    lo = (short)(__float_as_uint(l) >> 16);
}

// RNE fp32 -> bf16 (for single-plane rbf A-operand)
__device__ __forceinline__ short f2bf_rne(float v) {
    unsigned u = __float_as_uint(v);
    unsigned r = u + 0x7FFFu + ((u >> 16) & 1u);
    return (short)(r >> 16);
}

// ---- mj fragment buffer: per molecule 24576 shorts (hi 0..12287, lo 12288..) ----
// [ch(4096)][f(32)][grp(8)][e]; value (jl, f): ch=jl>>5, grp=(jl>>3)&3, e=jl&7
__device__ __forceinline__ void mj_store(short* mjTg, int gr, int f, float v) {
    int mol = gr / NPER;
    int jl  = gr - mol * NPER;
    short hi, lo; split2(v, hi, lo);
    size_t mo = (size_t)mol * 24576;
    int off = (jl >> 5) * 4096 + f * 32 + ((jl >> 3) & 3) * 8 + (jl & 7);
    mjTg[mo + off] = hi;
    mjTg[mo + 12288 + off] = lo;
}

// activation planes: [16 rows][128 f] shorts, 16B-slot XOR swizzle
__device__ __forceinline__ int plane_idx(int r, int f) {
    int s = f >> 3;
    int sp = (s & 8) | ((s ^ (r & 7)) & 7);
    return r * 128 + sp * 8 + (f & 7);
}

__device__ __forceinline__ void plane_store(short* Ahi, short* Alo, int r, int f, float v) {
    int idx = plane_idx(r, f);
    short hi, lo; split2(v, hi, lo);
    Ahi[idx] = hi; Alo[idx] = lo;
}

// 4-wave variant (k_first): wave stages its 16KB quarter (fq = 2w,2w+1)
__device__ __forceinline__ void stage_w_wave(short* dstBase, const short* srcBase, int w, int lane) {
#pragma unroll
    for (int it = 0; it < 16; ++it) {
        int boff = w * 16384 + it * 1024;
        __builtin_amdgcn_global_load_lds(
            (const __attribute__((address_space(1))) unsigned int*)((const char*)srcBase + boff + lane * 16),
            (__attribute__((address_space(3))) unsigned int*)((char*)dstBase + boff),
            16, 0, 0);
    }
}

// 8-wave variant: wave stages its 8KB eighth (fq = w)
__device__ __forceinline__ void stage_w_wave8(short* dstBase, const short* srcBase, int w, int lane) {
#pragma unroll
    for (int it = 0; it < 8; ++it) {
        int boff = w * 8192 + it * 1024;
        __builtin_amdgcn_global_load_lds(
            (const __attribute__((address_space(1))) unsigned int*)((const char*)srcBase + boff + lane * 16),
            (__attribute__((address_space(3))) unsigned int*)((char*)dstBase + boff),
            16, 0, 0);
    }
}

// 2-ft gemm (k_first): C[16 x 32] = planes @ W[:, fq0*16 .. fq0*16+31]
__device__ __forceinline__ void gemm_core(const short* Ahi, const short* Alo,
    const short* Wl, int lane, int fq0, f32x4 acc[2])
{
    const int r = lane & 15, h = lane >> 4;
    bf16x8 afh[4], afl[4];
#pragma unroll
    for (int kt = 0; kt < 4; ++kt) {
        int s = kt * 4 + h;
        int sp = (s & 8) | ((s ^ (r & 7)) & 7);
        afh[kt] = *(const bf16x8*)&Ahi[r * 128 + sp * 8];
        afl[kt] = *(const bf16x8*)&Alo[r * 128 + sp * 8];
    }
#pragma unroll
    for (int ft = 0; ft < 2; ++ft) {
        f32x4 a = {0.f, 0.f, 0.f, 0.f};
#pragma unroll
        for (int kt = 0; kt < 4; ++kt) {
            const short* bp = &Wl[((fq0 + ft) * 4 + kt) * 1024 + lane * 8];
            bf16x8 bh = *(const bf16x8*)bp;
            bf16x8 bl = *(const bf16x8*)(bp + 512);
            a = __builtin_amdgcn_mfma_f32_16x16x32_bf16(afh[kt], bl, a, 0, 0, 0);
            a = __builtin_amdgcn_mfma_f32_16x16x32_bf16(afl[kt], bh, a, 0, 0, 0);
            a = __builtin_amdgcn_mfma_f32_16x16x32_bf16(afh[kt], bh, a, 0, 0, 0);
        }
        acc[ft] = a;
    }
}

// 1-ft gemm (8-wave): C[16 x 16] = planes @ W[:, fq*16 .. fq*16+15]
__device__ __forceinline__ void gemm_core1(const short* Ahi, const short* Alo,
    const short* Wl, int lane, int fq, f32x4& acc)
{
    const int r = lane & 15, h = lane >> 4;
    bf16x8 afh[4], afl[4];
#pragma unroll
    for (int kt = 0; kt < 4; ++kt) {
        int s = kt * 4 + h;
        int sp = (s & 8) | ((s ^ (r & 7)) & 7);
        afh[kt] = *(const bf16x8*)&Ahi[r * 128 + sp * 8];
        afl[kt] = *(const bf16x8*)&Alo[r * 128 + sp * 8];
    }
    f32x4 a = {0.f, 0.f, 0.f, 0.f};
#pragma unroll
    for (int kt = 0; kt < 4; ++kt) {
        const short* bp = &Wl[(fq * 4 + kt) * 1024 + lane * 8];
        bf16x8 bh = *(const bf16x8*)bp;
        bf16x8 bl = *(const bf16x8*)(bp + 512);
        a = __builtin_amdgcn_mfma_f32_16x16x32_bf16(afh[kt], bl, a, 0, 0, 0);
        a = __builtin_amdgcn_mfma_f32_16x16x32_bf16(afl[kt], bh, a, 0, 0, 0);
        a = __builtin_amdgcn_mfma_f32_16x16x32_bf16(afh[kt], bh, a, 0, 0, 0);
    }
    acc = a;
}

// ---------------- weight prep + WrbfT transpose ----------------
__global__ __launch_bounds__(256) void k_prep(
    const float* __restrict__ Wi, const float* __restrict__ Wj,
    const float* __restrict__ rIW, const float* __restrict__ Wd,
    const float* __restrict__ rAW, const float* __restrict__ rOW,
    const float* __restrict__ Wrbf,
    short* __restrict__ prepW, float* __restrict__ WrbfT)
{
    const int m = blockIdx.x, tid = threadIdx.x;
    if (m >= 67) {
        // blocks 67..71: transpose Wrbf[b] -> [slot16][f128][4] fp32
        int bb = m - 67;
        const float* src = Wrbf + (size_t)bb * KR * FD;
        float* dst = WrbfT + (size_t)bb * KR * FD;
        for (int idx = tid; idx < KR * FD; idx += 256) {
            int k = idx >> 7, f = idx & 127;
            dst[(k >> 2) * 512 + f * 4 + (k & 3)] = src[idx];
        }
        return;
    }
    const float* src;
    if (m == 65) src = Wi;
    else if (m == 66) src = Wj;
    else {
        int bb = m / 13, slot = m % 13;
        switch (slot) {
            case 0: case 1: case 2: case 3:
                src = rIW + (size_t)((bb * 2 + (slot >> 1)) * 2 + (slot & 1)) * 16384; break;
            case 4: src = Wd + (size_t)bb * 16384; break;
            case 5: case 6: case 7: case 8: {
                int ss = slot - 5;
                src = rAW + (size_t)((bb * 2 + (ss >> 1)) * 2 + (ss & 1)) * 16384; break;
            }
            case 9:  src = Wi + (size_t)((bb + 1 < 5) ? (bb + 1) : 0) * 16384; break;
            case 10: src = Wj + (size_t)((bb + 1 < 5) ? (bb + 1) : 0) * 16384; break;
            default: src = rOW + (size_t)(bb * 2 + (slot - 11)) * 16384; break;
        }
    }
    short* dst = prepW + (size_t)m * 32768;
#pragma unroll
    for (int i = 0; i < 8; ++i) {
        int tr = tid + i * 256;
        int ft = tr >> 8, kt = (tr >> 6) & 3, l = tr & 63;
        int f = ft * 16 + (l & 15);
        int k0 = kt * 32 + (l >> 4) * 8;
        bf16x8 hi8, lo8;
#pragma unroll
        for (int e = 0; e < 8; ++e) {
            float v = src[(size_t)(k0 + e) * FD + f];
            short hh, ll; split2(v, hh, ll);
            hi8[e] = hh; lo8[e] = ll;
        }
        size_t o = (size_t)(ft * 4 + kt) * 1024 + (size_t)l * 8;
        *(bf16x8*)&dst[o] = hi8;
        *(bf16x8*)&dst[o + 512] = lo8;
    }
}

// ---------------- k_first (unchanged) ----------------
__global__ __launch_bounds__(256) void k_first(
    const int* __restrict__ Za, const float* __restrict__ emb,
    const short* __restrict__ Wprep,
    const float* __restrict__ bi, const float* __restrict__ bj,
    float* __restrict__ X, float* __restrict__ MI, short* __restrict__ mjTg,
    float* __restrict__ Ea, float* __restrict__ Qa)
{
    __shared__ short Ahi[2048], Alo[2048];
    __shared__ short Wl[2][32768];
    const int tid = threadIdx.x, lane = tid & 63, w = tid >> 6;
    const int row0 = blockIdx.x * 16;
    const int fq0 = w * 2;
    const int col0 = w * 32 + (lane & 15), col1 = col0 + 16;
    const int hh = lane >> 4;

    stage_w_wave(Wl[0], Wprep + (size_t)65 * 32768, w, lane);   // Wi(0)

    for (int idx = tid; idx < 2048; idx += 256) {
        int rr = idx >> 7, f = idx & 127;
        float v = emb[(size_t)Za[row0 + rr] * FD + f];
        X[(size_t)(row0 + rr) * FD + f] = v;
        plane_store(Ahi, Alo, rr, f, sspf(v));
    }
    if (tid < 16) { Ea[row0 + tid] = 0.f; Qa[row0 + tid] = 0.f; }
    if ((row0 % NPER) == 0) {
        short* mb = mjTg + (size_t)(row0 / NPER) * 24576;
        for (int idx = tid; idx < 2048; idx += 256) {
            int f = idx >> 4, t = idx & 15;
            mb[8192 + f * 32 + 16 + t] = 0;
            mb[12288 + 8192 + f * 32 + 16 + t] = 0;
        }
    }
    __syncthreads();

    stage_w_wave(Wl[1], Wprep + (size_t)66 * 32768, w, lane);   // Wj(0)

    f32x4 acc[2];
    gemm_core(Ahi, Alo, Wl[0], lane, fq0, acc);
    {
        float b0 = bi[col0], b1 = bi[col1];
#pragma unroll
        for (int reg = 0; reg < 4; ++reg) {
            int rw = hh * 4 + reg;
            MI[(size_t)(row0 + rw) * FD + col0] = sspf(acc[0][reg] + b0);
            MI[(size_t)(row0 + rw) * FD + col1] = sspf(acc[1][reg] + b1);
        }
    }
    asm volatile("s_waitcnt vmcnt(0)" ::: "memory");
    gemm_core(Ahi, Alo, Wl[1], lane, fq0, acc);
    {
        float b0 = bj[col0], b1 = bj[col1];
#pragma unroll
        for (int reg = 0; reg < 4; ++reg) {
            int gr = row0 + hh * 4 + reg;
            mj_store(mjTg, gr, col0, sspf(acc[0][reg] + b0));
            mj_store(mjTg, gr, col1, sspf(acc[1][reg] + b1));
        }
    }
}

// ---------------- k_fused: Phase M (2-MFMA message) + Phase T (13-GEMM chain) ----------------
__global__ __launch_bounds__(512, 2) void k_fused(
    const float* __restrict__ Ra, float* __restrict__ X,
    const short* __restrict__ Wprep, int b,
    const float* __restrict__ centers, const float* __restrict__ widths,
    const float* __restrict__ WrbfT,
    const float* __restrict__ rIb, const float* __restrict__ bd,
    const float* __restrict__ u, const float* __restrict__ rAb,
    const float* __restrict__ bi, const float* __restrict__ bj,
    const float* __restrict__ rOb, const float* __restrict__ Wout,
    const float* __restrict__ bout,
    float* __restrict__ MI, short* __restrict__ mjTg,
    float* __restrict__ Ea, float* __restrict__ Qa)
{
    __shared__ short Ahi[2048], Alo[2048];   // activation planes (8 KB)
    __shared__ char  uni[131072];            // 128 KB overlay
    __shared__ float mst[16][128];           // m staging, fp32 (8 KB)
    __shared__ float px[NPER], py[NPER], pz[NPER];
    __shared__ float eq[16][8][2];

    short* Bf  = (short*)uni;                // Phase M: [0,48K)
    short* Wl0 = (short*)uni;                // Phase T: [0,64K)
    short* Wl1 = (short*)(uni + 65536);      // Phase T: [64K,128K)

    const int tid = threadIdx.x, lane = tid & 63, w = tid >> 6;   // 8 waves
    const int row0 = blockIdx.x * 16;
    const int mol  = row0 / NPER;
    const int iloc0 = row0 - mol * NPER;
    const int NG = (b < 4) ? 13 : 11;
    const int col = lane & 15;
    const int grp = lane >> 4;
    const int hh  = lane >> 4;
    const int col0 = w * 16 + (lane & 15);

    auto lgOf = [&](int gg) { return (b < 4 || gg < 9) ? gg : gg + 2; };

    // ---- stage: Bf (48 KB molecule fragments), positions, X/MI regs ----
    {
        const char* src = (const char*)mjTg + (size_t)mol * 49152 + w * 6144 + lane * 16;
        char* dst = (char*)Bf + w * 6144;
#pragma unroll
        for (int it = 0; it < 6; ++it) {
            __builtin_amdgcn_global_load_lds(
                (const __attribute__((address_space(1))) unsigned int*)(src + it * 1024),
                (__attribute__((address_space(3))) unsigned int*)(dst + it * 1024),
                16, 0, 0);
        }
    }
    if (tid < NPER) {
        px[tid] = Ra[(size_t)(mol * NPER + tid) * 3 + 0];
        py[tid] = Ra[(size_t)(mol * NPER + tid) * 3 + 1];
        pz[tid] = Ra[(size_t)(mol * NPER + tid) * 3 + 2];
    }
    float xreg[4];
#pragma unroll
    for (int reg = 0; reg < 4; ++reg)
        xreg[reg] = X[(size_t)(row0 + hh * 4 + reg) * FD + col0];
    float mi0l = MI[(size_t)(row0 + 2 * w) * FD + lane];
    float mi0h = MI[(size_t)(row0 + 2 * w) * FD + 64 + lane];
    float mi1l = MI[(size_t)(row0 + 2 * w + 1) * FD + lane];
    float mi1h = MI[(size_t)(row0 + 2 * w + 1) * FD + 64 + lane];

    float cent[4], wid[4];
#pragma unroll
    for (int kt = 0; kt < 4; ++kt) {
        cent[kt] = centers[kt * 16 + col];
        wid[kt]  = widths[kt * 16 + col];
    }

    __syncthreads();   // full drain: Bf, positions ready

    // ---------------- Phase M: 2 atoms per wave, single-bf16 A (2 MFMAs) ----------------
#pragma unroll
    for (int a2 = 0; a2 < 2; ++a2) {
        const int rl = 2 * w + a2;
        const int i  = iloc0 + rl;
        const float xi = px[i], yi = py[i], zi = pz[i];

        f32x4 acc[4][8];
#pragma unroll
        for (int kt = 0; kt < 4; ++kt)
#pragma unroll
            for (int ft = 0; ft < 8; ++ft)
                acc[kt][ft] = (f32x4){0.f, 0.f, 0.f, 0.f};

        for (int ch = 0; ch < 3; ++ch) {
            bf16x8 Fhi[4];
#pragma unroll
            for (int e = 0; e < 8; ++e) {
                int jg = ch * 32 + grp * 8 + e;
                float ed = 0.f, cut = 0.f;
                if (jg < NPER) {
                    float dx = px[jg] - xi, dy = py[jg] - yi, dz = pz[jg] - zi;
                    float d = sqrtf(dx * dx + dy * dy + dz * dz);
                    ed = __expf(-d);
                    if (jg != i && d < SR_CUT_C) {
                        float xr = d * (1.0f / SR_CUT_C);
                        float xr2 = xr * xr, xr3 = xr2 * xr;
                        cut = 1.0f - xr3 * (6.0f * xr2 - 15.0f * xr + 10.0f);
                    }
                }
#pragma unroll
                for (int kt = 0; kt < 4; ++kt) {
                    float t = ed - cent[kt];
                    float a2v = wid[kt] * t * t;
                    // bf16 A-plane: values < e^-7 are below quantization relevance
                    if (__any(a2v < 7.0f)) {
                        Fhi[kt][e] = f2bf_rne(cut * __expf(-a2v));
                    } else {
                        Fhi[kt][e] = 0;
                    }
                }
            }
            const int cb = ch * 4096 + col * 32 + grp * 8;
#pragma unroll
            for (int ft = 0; ft < 8; ++ft) {
                bf16x8 bhi = *(const bf16x8*)&Bf[cb + ft * 512];
                bf16x8 blo = *(const bf16x8*)&Bf[12288 + cb + ft * 512];
                __builtin_amdgcn_s_setprio(1);
#pragma unroll
                for (int kt = 0; kt < 4; ++kt) {
                    acc[kt][ft] = __builtin_amdgcn_mfma_f32_16x16x32_bf16(Fhi[kt], bhi, acc[kt][ft], 0, 0, 0);
                    acc[kt][ft] = __builtin_amdgcn_mfma_f32_16x16x32_bf16(Fhi[kt], blo, acc[kt][ft], 0, 0, 0);
                }
                __builtin_amdgcn_s_setprio(0);
            }
        }

        // contract with WrbfT (global, L2-hot, contiguous float4); reduce over k
        float part[8];
#pragma unroll
        for (int ft = 0; ft < 8; ++ft) part[ft] = 0.f;
#pragma unroll
        for (int kt = 0; kt < 4; ++kt) {
            const float* wrow = &WrbfT[(kt * 4 + grp) * 512 + col * 4];
#pragma unroll
            for (int ft = 0; ft < 8; ++ft) {
                float4 w4 = *(const float4*)(wrow + ft * 64);
                part[ft] += acc[kt][ft].x * w4.x + acc[kt][ft].y * w4.y
                          + acc[kt][ft].z * w4.z + acc[kt][ft].w * w4.w;
            }
        }
#pragma unroll
        for (int ft = 0; ft < 8; ++ft) {
            part[ft] += __shfl_xor(part[ft], 16);
            part[ft] += __shfl_xor(part[ft], 32);
        }
        float p0 = (grp == 0) ? part[0] : (grp == 1) ? part[1] : (grp == 2) ? part[2] : part[3];
        float p1 = (grp == 0) ? part[4] : (grp == 1) ? part[5] : (grp == 2) ? part[6] : part[7];
        float m0 = (a2 ? mi1l : mi0l) + p0;
        float m1 = (a2 ? mi1h : mi0h) + p1;
        mst[rl][lane]      = m0;
        mst[rl][64 + lane] = m1;
        plane_store(Ahi, Alo, rl, lane,      sspf(m0));
        plane_store(Ahi, Alo, rl, 64 + lane, sspf(m1));
    }

    __syncthreads();   // Phase M complete: Bf dead, mst + planes ready

    stage_w_wave8(Wl0, Wprep + (size_t)(b * 13 + lgOf(0)) * 32768, w, lane);

    float vreg[4];
#pragma unroll
    for (int reg = 0; reg < 4; ++reg)
        vreg[reg] = mst[hh * 4 + reg][col0];

    // ---------------- Phase T: 13-GEMM chain ----------------
    f32x4 acc1;
    for (int g = 0; g < NG; ++g) {
        const int cur = g & 1;
        short* Wcur = cur ? Wl1 : Wl0;
        short* Wnxt = cur ? Wl0 : Wl1;
        if (g > 0)
            asm volatile("s_waitcnt lgkmcnt(0)\n\ts_barrier" ::: "memory");
        asm volatile("s_waitcnt vmcnt(0)" ::: "memory");
        if (g + 1 < NG)
            stage_w_wave8(Wnxt, Wprep + (size_t)(b * 13 + lgOf(g + 1)) * 32768, w, lane);

        int lg = lgOf(g);
        const float* bptr;
        switch (lg) {
            case 0:  bptr = rIb + ((size_t)(b * 2 + 0) * 2 + 0) * FD; break;
            case 1:  bptr = rIb + ((size_t)(b * 2 + 0) * 2 + 1) * FD; break;
            case 2:  bptr = rIb + ((size_t)(b * 2 + 1) * 2 + 0) * FD; break;
            case 3:  bptr = rIb + ((size_t)(b * 2 + 1) * 2 + 1) * FD; break;
            case 4:  bptr = bd + (size_t)b * FD; break;
            case 5:  bptr = rAb + ((size_t)(b * 2 + 0) * 2 + 0) * FD; break;
            case 6:  bptr = rAb + ((size_t)(b * 2 + 0) * 2 + 1) * FD; break;
            case 7:  bptr = rAb + ((size_t)(b * 2 + 1) * 2 + 0) * FD; break;
            case 8:  bptr = rAb + ((size_t)(b * 2 + 1) * 2 + 1) * FD; break;
            case 9:  bptr = bi + (size_t)(b + 1) * FD; break;
            case 10: bptr = bj + (size_t)(b + 1) * FD; break;
            case 11: bptr = rOb + (size_t)(b * 2 + 0) * FD; break;
            default: bptr = rOb + (size_t)(b * 2 + 1) * FD; break;
        }
        float bv0 = bptr[col0];
        float uv0 = 0.f;
        if (lg == 4) uv0 = u[(size_t)b * FD + col0];

        gemm_core1(Ahi, Alo, Wcur, lane, w, acc1);

        asm volatile("s_waitcnt lgkmcnt(0)\n\ts_barrier" ::: "memory");

        const bool isT = (lg == 0) | (lg == 2) | (lg == 5) | (lg == 7) | (lg == 11);
        const bool isV = (lg == 1) | (lg == 3) | (lg == 6) | (lg == 8) | (lg == 12);
        if (isT) {
#pragma unroll
            for (int reg = 0; reg < 4; ++reg)
                plane_store(Ahi, Alo, hh * 4 + reg, col0, sspf(acc1[reg] + bv0));
        } else if (isV) {
#pragma unroll
            for (int reg = 0; reg < 4; ++reg) {
                int rw = hh * 4 + reg;
                float nv0 = acc1[reg] + bv0 + vreg[reg];
                vreg[reg] = nv0;
                if (lg != 12) plane_store(Ahi, Alo, rw, col0, sspf(nv0));
                if (lg == 8)  X[(size_t)(row0 + rw) * FD + col0] = nv0;
            }
        } else if (lg == 4) {
#pragma unroll
            for (int reg = 0; reg < 4; ++reg) {
                float nv0 = acc1[reg] + bv0 + uv0 * xreg[reg];
                vreg[reg] = nv0;
                plane_store(Ahi, Alo, hh * 4 + reg, col0, sspf(nv0));
            }
        } else if (lg == 9) {
#pragma unroll
            for (int reg = 0; reg < 4; ++reg)
                MI[(size_t)(row0 + hh * 4 + reg) * FD + col0] = sspf(acc1[reg] + bv0);
        } else {   // lg == 10: mj for next block -> fragment layout
#pragma unroll
            for (int reg = 0; reg < 4; ++reg)
                mj_store(mjTg, row0 + hh * 4 + reg, col0, sspf(acc1[reg] + bv0));
        }
    }

    // output projection: e/q = ssp(o) @ Wout + bout
    float pe[4], pq[4];
#pragma unroll
    for (int reg = 0; reg < 4; ++reg) {
        float s0 = sspf(vreg[reg]);
        pe[reg] = s0 * Wout[col0 * 2 + 0];
        pq[reg] = s0 * Wout[col0 * 2 + 1];
#pragma unroll
        for (int mk = 1; mk < 16; mk <<= 1) {
            pe[reg] += __shfl_xor(pe[reg], mk);
            pq[reg] += __shfl_xor(pq[reg], mk);
        }
        if ((lane & 15) == 0) {
            eq[hh * 4 + reg][w][0] = pe[reg];
            eq[hh * 4 + reg][w][1] = pq[reg];
        }
    }
    __syncthreads();
    if (tid < 16) {
        float e = 0.f, q = 0.f;
#pragma unroll
        for (int ww = 0; ww < 8; ++ww) { e += eq[tid][ww][0]; q += eq[tid][ww][1]; }
        Ea[row0 + tid] += e + bout[0];
        Qa[row0 + tid] += q + bout[1];
    }
}

// ---------------- finale (unchanged) ----------------
__global__ __launch_bounds__(256) void k_final(
    const int* __restrict__ Za, const float* __restrict__ Ra,
    const float* __restrict__ Escale, const float* __restrict__ Eshift,
    const float* __restrict__ Qscale, const float* __restrict__ Qshift,
    const float* __restrict__ Ea, const float* __restrict__ Qa,
    float* __restrict__ out)
{
    __shared__ float qs[NPER], es[NPER], px[NPER], py[NPER], pz[NPER];
    __shared__ float red[256];
    const int mol = blockIdx.x, t = threadIdx.x;
    float q = 0.f;
    if (t < NPER) {
        int a = mol * NPER + t;
        int z = Za[a];
        es[t] = Escale[z] * Ea[a] + Eshift[z];
        q = Qscale[z] * Qa[a] + Qshift[z];
        px[t] = Ra[(size_t)a * 3 + 0];
        py[t] = Ra[(size_t)a * 3 + 1];
        pz[t] = Ra[(size_t)a * 3 + 2];
    }
    red[t] = q;
    __syncthreads();
    for (int s = 128; s > 0; s >>= 1) {
        if (t < s) red[t] += red[t + s];
        __syncthreads();
    }
    float qavg = red[0] / (float)NPER;
    __syncthreads();
    if (t < NPER) qs[t] = q - qavg;
    red[t] = 0.f;
    __syncthreads();

    float local = 0.f;
    const float c = SR_CUT_C * 0.5f;
    for (int p = t; p < NPER * NPER; p += 256) {
        int i = p / NPER, j = p % NPER;
        if (i == j) continue;
        float dx = px[i] - px[j], dy = py[i] - py[j], dz = pz[i] - pz[j];
        float d2 = dx * dx + dy * dy + dz * dz;
        float d = sqrtf(d2);
        float dS = sqrtf(d2 + 1.0f);
        float sw;
        if (d < c) {
            float xs = d / c;
            float xs2 = xs * xs, xs3 = xs2 * xs;
            sw = xs3 * (6.0f * xs2 - 15.0f * xs + 10.0f);
        } else {
            sw = 1.0f;
        }
        local += KEHALF_C * qs[i] * qs[j] * ((1.0f - sw) / dS + sw / d);
    }
    for (int a = t; a < NPER; a += 256) local += es[a];
    red[t] = local;
    __syncthreads();
    for (int s = 128; s > 0; s >>= 1) {
        if (t < s) red[t] += red[t + s];
        __syncthreads();
    }
    if (t == 0) out[mol] = red[0];
}

extern "C" void kernel_launch(void* const* d_in, const int* in_sizes, int n_in,
                              void* d_out, int out_size, void* d_ws, size_t ws_size,
                              hipStream_t stream)
{
    (void)in_sizes; (void)n_in; (void)out_size; (void)ws_size;

    const int*   Za     = (const int*)d_in[0];
    const float* Ra     = (const float*)d_in[1];
    const float* emb    = (const float*)d_in[5];
    const float* rbfc   = (const float*)d_in[6];
    const float* rbfw   = (const float*)d_in[7];
    const float* Wrbf   = (const float*)d_in[8];
    const float* Wi     = (const float*)d_in[9];
    const float* bi     = (const float*)d_in[10];
    const float* Wj     = (const float*)d_in[11];
    const float* bj     = (const float*)d_in[12];
    const float* rIW    = (const float*)d_in[13];
    const float* rIb    = (const float*)d_in[14];
    const float* Wd     = (const float*)d_in[15];
    const float* bd     = (const float*)d_in[16];
    const float* u      = (const float*)d_in[17];
    const float* rAW    = (const float*)d_in[18];
    const float* rAb    = (const float*)d_in[19];
    const float* rOW    = (const float*)d_in[20];
    const float* rOb    = (const float*)d_in[21];
    const float* Wout   = (const float*)d_in[22];
    const float* bout   = (const float*)d_in[23];
    const float* Escale = (const float*)d_in[24];
    const float* Eshift = (const float*)d_in[25];
    const float* Qscale = (const float*)d_in[26];
    const float* Qshift = (const float*)d_in[27];
    float* outp = (float*)d_out;

    float* ws = (float*)d_ws;
    const size_t NF = (size_t)NATOM * FD;
    float* x  = ws;
    float* mi = ws + NF;
    float* Ea = ws + 2 * NF;
    float* Qa = Ea + NATOM;
    short* prepW = (short*)(ws + 2 * NF + 2 * NATOM);
    short* mjTg  = prepW + (size_t)67 * 32768;
    float* WrbfT = (float*)(mjTg + (size_t)NMOL * 24576);

    k_prep<<<72, 256, 0, stream>>>(Wi, Wj, rIW, Wd, rAW, rOW, Wrbf, prepW, WrbfT);
    k_first<<<NATOM / 16, 256, 0, stream>>>(Za, emb, prepW, bi, bj, x, mi, mjTg, Ea, Qa);

    for (int b = 0; b < NBLOCK; ++b) {
        k_fused<<<NATOM / 16, 512, 0, stream>>>(
            Ra, x, prepW, b, rbfc, rbfw, WrbfT + (size_t)b * KR * FD,
            rIb, bd, u, rAb, bi, bj, rOb,
            Wout + (size_t)b * FD * 2, bout + b * 2, mi, mjTg, Ea, Qa);
    }

    k_final<<<NMOL, 256, 0, stream>>>(Za, Ra, Escale, Eshift, Qscale, Qshift, Ea, Qa, outp);
}